// Round 2
// baseline (545.274 us; speedup 1.0000x reference)
//
#include <hip/hip_runtime.h>

// SimGRew: Wmat = relu(S - prob + 0.5*A_sel) * same-graph-block mask
//   S = (X_hat @ X_hat^T) / ||X_hat||_F^2,  X_hat = x @ W0^T + b0
//   A_sel[i,j] = A[batch[i], i, j] (local-index adjacency) -> nonzero only for
//   i,j < NPG, i.e. ONLY graph 0's diagonal block sees the +alpha*A term.
// Outputs flat: Wmat[N*N] f32, edge_ratio, prob.

#define NN   4096
#define GG   8
#define NPG  512
#define FF   128
#define HH   128
#define NE   131072
#define ALPHA 0.5f

// workspace layout (bytes):
//   [0, 1MiB)        : Acnt  int[NPG*NPG]   (graph-0 adjacency counts only)
//   [1MiB, 1MiB+64)  : meta  offs[8] ints | normsq f32 @+32 | nz int @+36 | done int @+40
#define ACNT_BYTES ((size_t)NPG * NPG * 4)
#define META_OFF   ACNT_BYTES

__global__ __launch_bounds__(256) void k_offsets(const int4* __restrict__ batch4,
                                                 int* __restrict__ offs) {
    __shared__ int cnt[GG];
    int tid = threadIdx.x;
    if (tid < GG) cnt[tid] = 0;
    __syncthreads();
    for (int i = tid; i < NN / 4; i += 256) {
        int4 b = batch4[i];
        atomicAdd(&cnt[b.x], 1); atomicAdd(&cnt[b.y], 1);
        atomicAdd(&cnt[b.z], 1); atomicAdd(&cnt[b.w], 1);
    }
    __syncthreads();
    if (tid == 0) {
        int run = 0;
        for (int g = 0; g < GG; ++g) { offs[g] = run; run += cnt[g]; }
    }
}

// Only graph-0 edges can ever be selected (A_sel rows/cols < NPG); build Acnt[0] only.
__global__ __launch_bounds__(256) void k_scatter(const int* __restrict__ ei,
                                                 const int* __restrict__ batch,
                                                 const int* __restrict__ offs,
                                                 int* __restrict__ Acnt) {
    int e = blockIdx.x * 256 + threadIdx.x;
    if (e >= NE) return;
    int src = ei[e], dst = ei[NE + e];
    int g = batch[src];
    if (g != 0) return;
    int lu = src - offs[0];
    int lv = dst - offs[batch[dst]];
    if (lu >= 0 && lu < NPG && lv >= 0 && lv < NPG)
        atomicAdd(&Acnt[lu * NPG + lv], 1);
}

// X_hat = x @ W0^T + b0 ; accumulate ||X_hat||^2 into *normsq.
// 64x64 tile / block, 16x16 threads, 4x4 acc, K-chunks of 16.
__global__ __launch_bounds__(256) void k_xhat(const float* __restrict__ x,
                                              const float* __restrict__ W0,
                                              const float* __restrict__ b0,
                                              float* __restrict__ Xh,
                                              float* __restrict__ normsq) {
    __shared__ float As[16][68];
    __shared__ float Bs[16][68];
    __shared__ float red[256];

    int bx = blockIdx.x;                 // 64 m-tiles x 2 n-tiles = 128 blocks
    int tm = bx >> 1, tn = bx & 1;
    int r0 = tm * 64, j0 = tn * 64;
    int tid = threadIdx.x;
    int tx = tid & 15, ty = tid >> 4;
    int li = tid & 63, kq = tid >> 6;

    float acc[4][4];
#pragma unroll
    for (int i = 0; i < 4; ++i)
#pragma unroll
        for (int j = 0; j < 4; ++j) acc[i][j] = 0.f;

    for (int k0 = 0; k0 < FF; k0 += 16) {
        float4 av = *(const float4*)&x [(size_t)(r0 + li) * FF + k0 + kq * 4];
        float4 bv = *(const float4*)&W0[(size_t)(j0 + li) * FF + k0 + kq * 4];
        As[kq*4+0][li] = av.x; As[kq*4+1][li] = av.y;
        As[kq*4+2][li] = av.z; As[kq*4+3][li] = av.w;
        Bs[kq*4+0][li] = bv.x; Bs[kq*4+1][li] = bv.y;
        Bs[kq*4+2][li] = bv.z; Bs[kq*4+3][li] = bv.w;
        __syncthreads();
#pragma unroll
        for (int k = 0; k < 16; ++k) {
            float4 a = *(const float4*)&As[k][ty * 4];
            float4 b = *(const float4*)&Bs[k][tx * 4];
            float ar[4] = {a.x, a.y, a.z, a.w};
            float br[4] = {b.x, b.y, b.z, b.w};
#pragma unroll
            for (int i = 0; i < 4; ++i)
#pragma unroll
                for (int j = 0; j < 4; ++j) acc[i][j] += ar[i] * br[j];
        }
        __syncthreads();
    }

    float4 bb = *(const float4*)&b0[j0 + tx * 4];
    float ss = 0.f;
#pragma unroll
    for (int ii = 0; ii < 4; ++ii) {
        int row = r0 + ty * 4 + ii;
        float4 v;
        v.x = acc[ii][0] + bb.x;
        v.y = acc[ii][1] + bb.y;
        v.z = acc[ii][2] + bb.z;
        v.w = acc[ii][3] + bb.w;
        *(float4*)&Xh[(size_t)row * HH + j0 + tx * 4] = v;
        ss += v.x * v.x + v.y * v.y + v.z * v.z + v.w * v.w;
    }

    red[tid] = ss;
    __syncthreads();
    for (int s = 128; s > 0; s >>= 1) {
        if (tid < s) red[tid] += red[tid + s];
        __syncthreads();
    }
    if (tid == 0) atomicAdd(normsq, red[0]);
}

// One kernel covers the whole 4096x4096 output in 64x64 tiles (4096 blocks).
// First 512 blocks: diagonal-group tiles -> GEMM + relu + A + nnz count.
// Remaining 3584 blocks: stream float4 zeros.
// Last finished block writes edge_ratio and prob.
__global__ __launch_bounds__(256) void k_fused(const float* __restrict__ Xh,
                                               const int* __restrict__ Acnt,
                                               const float* __restrict__ normsq,
                                               const float* __restrict__ prob,
                                               float* __restrict__ out,
                                               int* __restrict__ nz,
                                               int* __restrict__ done) {
    __shared__ float As[16][68];
    __shared__ float Bs[16][68];
    __shared__ int redi[256];

    int bt = blockIdx.x;
    int tid = threadIdx.x;

    if (bt < 512) {
        // diagonal tiles: gb in [0,8), 8x8 tile grid per graph block
        int gb = bt >> 6;
        int t  = bt & 63;
        int tm = t >> 3, tn = t & 7;
        int base = gb * NPG;
        int r0 = base + tm * 64, c0 = base + tn * 64;
        int tx = tid & 15, ty = tid >> 4;
        int li = tid & 63, kq = tid >> 6;

        float acc[4][4];
#pragma unroll
        for (int i = 0; i < 4; ++i)
#pragma unroll
            for (int j = 0; j < 4; ++j) acc[i][j] = 0.f;

        for (int k0 = 0; k0 < HH; k0 += 16) {
            float4 av = *(const float4*)&Xh[(size_t)(r0 + li) * HH + k0 + kq * 4];
            float4 bv = *(const float4*)&Xh[(size_t)(c0 + li) * HH + k0 + kq * 4];
            As[kq*4+0][li] = av.x; As[kq*4+1][li] = av.y;
            As[kq*4+2][li] = av.z; As[kq*4+3][li] = av.w;
            Bs[kq*4+0][li] = bv.x; Bs[kq*4+1][li] = bv.y;
            Bs[kq*4+2][li] = bv.z; Bs[kq*4+3][li] = bv.w;
            __syncthreads();
#pragma unroll
            for (int k = 0; k < 16; ++k) {
                float4 a = *(const float4*)&As[k][ty * 4];
                float4 b = *(const float4*)&Bs[k][tx * 4];
                float ar[4] = {a.x, a.y, a.z, a.w};
                float br[4] = {b.x, b.y, b.z, b.w};
#pragma unroll
                for (int i = 0; i < 4; ++i)
#pragma unroll
                    for (int j = 0; j < 4; ++j) acc[i][j] += ar[i] * br[j];
            }
            __syncthreads();
        }

        float inv = 1.0f / (*normsq);
        float p = prob[0];
        int cnt = 0;
#pragma unroll
        for (int ii = 0; ii < 4; ++ii) {
            int row = r0 + ty * 4 + ii;
            float4 v;
            float w[4];
#pragma unroll
            for (int jj = 0; jj < 4; ++jj) {
                int col = c0 + tx * 4 + jj;
                float s = acc[ii][jj] * inv;
                float a = 0.f;
                if (gb == 0)   // only graph 0 sees A (local-index quirk)
                    a = (float)Acnt[row * NPG + col];
                float pre = s - p + ALPHA * a;
                w[jj] = pre > 0.f ? pre : 0.f;
                cnt += (pre > 0.f) ? 1 : 0;
            }
            v.x = w[0]; v.y = w[1]; v.z = w[2]; v.w = w[3];
            *(float4*)&out[(size_t)row * NN + c0 + tx * 4] = v;
        }

        redi[tid] = cnt;
        __syncthreads();
        for (int s = 128; s > 0; s >>= 1) {
            if (tid < s) redi[tid] += redi[tid + s];
            __syncthreads();
        }
        if (tid == 0) atomicAdd(nz, redi[0]);
    } else {
        // off-diagonal tile: enumerate 56 off-diag tile-cols per tile-row
        int idx = bt - 512;                 // [0, 3584)
        int tr = idx / 56;
        int k  = idx - tr * 56;
        int grp = tr >> 3;
        int tc = (k >= grp * 8) ? (k + 8) : k;
        int r0 = tr * 64, c0 = tc * 64;
        float4 z = make_float4(0.f, 0.f, 0.f, 0.f);
        int row = r0 + (tid >> 4);
        int col = c0 + (tid & 15) * 4;
#pragma unroll
        for (int ii = 0; ii < 4; ++ii)
            *(float4*)&out[(size_t)(row + ii * 16) * NN + col] = z;
    }

    // completion: last block writes edge_ratio + prob
    __threadfence();
    if (tid == 0) {
        int d = atomicAdd(done, 1);
        if (d == (int)gridDim.x - 1) {
            int total = atomicAdd(nz, 0);   // device-scope read
            out[(size_t)NN * NN]     = (float)total / (float)NE;
            out[(size_t)NN * NN + 1] = prob[0];
        }
    }
}

extern "C" void kernel_launch(void* const* d_in, const int* in_sizes, int n_in,
                              void* d_out, int out_size, void* d_ws, size_t ws_size,
                              hipStream_t stream) {
    (void)in_sizes; (void)n_in; (void)out_size; (void)ws_size;
    const float* x    = (const float*)d_in[0];
    const float* W0   = (const float*)d_in[1];
    const float* b0   = (const float*)d_in[2];
    const float* prob = (const float*)d_in[3];
    const int*   ei   = (const int*)d_in[4];
    const int*   bat  = (const int*)d_in[5];
    float* out = (float*)d_out;
    char*  ws  = (char*)d_ws;

    int*   Acnt   = (int*)ws;
    int*   offs   = (int*)(ws + META_OFF);
    float* normsq = (float*)(ws + META_OFF + 32);
    int*   nz     = (int*)(ws + META_OFF + 36);
    int*   done   = (int*)(ws + META_OFF + 40);

    // Xh after meta (aligned to 256B)
    float* Xh = (float*)(ws + ((META_OFF + 64 + 255) & ~(size_t)255));

    // zero Acnt + meta only (1 MiB + 64 B) — output zeroing is fused into k_fused
    hipMemsetAsync(ws, 0, ACNT_BYTES + 64, stream);

    k_offsets<<<1, 256, 0, stream>>>((const int4*)bat, offs);
    k_xhat<<<128, 256, 0, stream>>>(x, W0, b0, Xh, normsq);
    k_scatter<<<NE / 256, 256, 0, stream>>>(ei, bat, offs, Acnt);
    k_fused<<<4096, 256, 0, stream>>>(Xh, Acnt, normsq, prob, out, nz, done);
}

// Round 3
// 120.687 us; speedup vs baseline: 4.5181x; 4.5181x over previous
//
#include <hip/hip_runtime.h>

// SimGRew: Wmat = relu(S - prob + 0.5*A_sel) * same-graph-block mask
//   S = (X_hat @ X_hat^T) / ||X_hat||_F^2,  X_hat = x @ W0^T + b0
//   A_sel[i,j] = A[batch[i], i, j] (local-index adjacency) -> nonzero only for
//   i,j < NPG, i.e. ONLY graph 0's diagonal block sees the +alpha*A term.
// Outputs flat: Wmat[N*N] f32, edge_ratio, prob.
//
// R3: removed __threadfence/last-block-done protocol (R2 regression: device-scope
// fence from every thread of 4096 blocks -> L2 wb/inv storm, 461us @ 2% HBM).
// Final scalars via separate 1-thread dispatch (kernel boundary = coherence).

#define NN   4096
#define GG   8
#define NPG  512
#define FF   128
#define HH   128
#define NE   131072
#define ALPHA 0.5f

// workspace layout (bytes):
//   [0, 1MiB)        : Acnt  int[NPG*NPG]   (graph-0 adjacency counts only)
//   [1MiB, 1MiB+64)  : meta  offs[8] ints | normsq f32 @+32 | nz int @+36
//   [aligned]        : Xh    float[NN*HH]
#define ACNT_BYTES ((size_t)NPG * NPG * 4)
#define META_OFF   ACNT_BYTES

__global__ __launch_bounds__(256) void k_offsets(const int4* __restrict__ batch4,
                                                 int* __restrict__ offs) {
    __shared__ int cnt[GG];
    int tid = threadIdx.x;
    if (tid < GG) cnt[tid] = 0;
    __syncthreads();
    for (int i = tid; i < NN / 4; i += 256) {
        int4 b = batch4[i];
        atomicAdd(&cnt[b.x], 1); atomicAdd(&cnt[b.y], 1);
        atomicAdd(&cnt[b.z], 1); atomicAdd(&cnt[b.w], 1);
    }
    __syncthreads();
    if (tid == 0) {
        int run = 0;
        for (int g = 0; g < GG; ++g) { offs[g] = run; run += cnt[g]; }
    }
}

// Only graph-0 edges can ever be selected (A_sel rows/cols < NPG); build Acnt[0] only.
__global__ __launch_bounds__(256) void k_scatter(const int* __restrict__ ei,
                                                 const int* __restrict__ batch,
                                                 const int* __restrict__ offs,
                                                 int* __restrict__ Acnt) {
    int e = blockIdx.x * 256 + threadIdx.x;
    if (e >= NE) return;
    int src = ei[e], dst = ei[NE + e];
    int g = batch[src];
    if (g != 0) return;
    int lu = src - offs[0];
    int lv = dst - offs[batch[dst]];
    if (lu >= 0 && lu < NPG && lv >= 0 && lv < NPG)
        atomicAdd(&Acnt[lu * NPG + lv], 1);
}

// X_hat = x @ W0^T + b0 ; accumulate ||X_hat||^2 into *normsq.
// 64x64 tile / block, 16x16 threads, 4x4 acc, K-chunks of 16.
__global__ __launch_bounds__(256) void k_xhat(const float* __restrict__ x,
                                              const float* __restrict__ W0,
                                              const float* __restrict__ b0,
                                              float* __restrict__ Xh,
                                              float* __restrict__ normsq) {
    __shared__ float As[16][68];
    __shared__ float Bs[16][68];
    __shared__ float red[256];

    int bx = blockIdx.x;                 // 64 m-tiles x 2 n-tiles = 128 blocks
    int tm = bx >> 1, tn = bx & 1;
    int r0 = tm * 64, j0 = tn * 64;
    int tid = threadIdx.x;
    int tx = tid & 15, ty = tid >> 4;
    int li = tid & 63, kq = tid >> 6;

    float acc[4][4];
#pragma unroll
    for (int i = 0; i < 4; ++i)
#pragma unroll
        for (int j = 0; j < 4; ++j) acc[i][j] = 0.f;

    for (int k0 = 0; k0 < FF; k0 += 16) {
        float4 av = *(const float4*)&x [(size_t)(r0 + li) * FF + k0 + kq * 4];
        float4 bv = *(const float4*)&W0[(size_t)(j0 + li) * FF + k0 + kq * 4];
        As[kq*4+0][li] = av.x; As[kq*4+1][li] = av.y;
        As[kq*4+2][li] = av.z; As[kq*4+3][li] = av.w;
        Bs[kq*4+0][li] = bv.x; Bs[kq*4+1][li] = bv.y;
        Bs[kq*4+2][li] = bv.z; Bs[kq*4+3][li] = bv.w;
        __syncthreads();
#pragma unroll
        for (int k = 0; k < 16; ++k) {
            float4 a = *(const float4*)&As[k][ty * 4];
            float4 b = *(const float4*)&Bs[k][tx * 4];
            float ar[4] = {a.x, a.y, a.z, a.w};
            float br[4] = {b.x, b.y, b.z, b.w};
#pragma unroll
            for (int i = 0; i < 4; ++i)
#pragma unroll
                for (int j = 0; j < 4; ++j) acc[i][j] += ar[i] * br[j];
        }
        __syncthreads();
    }

    float4 bb = *(const float4*)&b0[j0 + tx * 4];
    float ss = 0.f;
#pragma unroll
    for (int ii = 0; ii < 4; ++ii) {
        int row = r0 + ty * 4 + ii;
        float4 v;
        v.x = acc[ii][0] + bb.x;
        v.y = acc[ii][1] + bb.y;
        v.z = acc[ii][2] + bb.z;
        v.w = acc[ii][3] + bb.w;
        *(float4*)&Xh[(size_t)row * HH + j0 + tx * 4] = v;
        ss += v.x * v.x + v.y * v.y + v.z * v.z + v.w * v.w;
    }

    red[tid] = ss;
    __syncthreads();
    for (int s = 128; s > 0; s >>= 1) {
        if (tid < s) red[tid] += red[tid + s];
        __syncthreads();
    }
    if (tid == 0) atomicAdd(normsq, red[0]);
}

// One kernel covers the whole 4096x4096 output in 64x64 tiles (4096 blocks).
// First 512 blocks: diagonal-group tiles -> GEMM + relu + A + nnz count.
// Remaining 3584 blocks: stream float4 zeros. NO fence, NO completion protocol.
__global__ __launch_bounds__(256) void k_fused(const float* __restrict__ Xh,
                                               const int* __restrict__ Acnt,
                                               const float* __restrict__ normsq,
                                               const float* __restrict__ prob,
                                               float* __restrict__ out,
                                               int* __restrict__ nz) {
    __shared__ float As[16][68];
    __shared__ float Bs[16][68];
    __shared__ int redi[256];

    int bt = blockIdx.x;
    int tid = threadIdx.x;

    if (bt < 512) {
        // diagonal tiles: gb in [0,8), 8x8 tile grid per graph block
        int gb = bt >> 6;
        int t  = bt & 63;
        int tm = t >> 3, tn = t & 7;
        int base = gb * NPG;
        int r0 = base + tm * 64, c0 = base + tn * 64;
        int tx = tid & 15, ty = tid >> 4;
        int li = tid & 63, kq = tid >> 6;

        float acc[4][4];
#pragma unroll
        for (int i = 0; i < 4; ++i)
#pragma unroll
            for (int j = 0; j < 4; ++j) acc[i][j] = 0.f;

        for (int k0 = 0; k0 < HH; k0 += 16) {
            float4 av = *(const float4*)&Xh[(size_t)(r0 + li) * HH + k0 + kq * 4];
            float4 bv = *(const float4*)&Xh[(size_t)(c0 + li) * HH + k0 + kq * 4];
            As[kq*4+0][li] = av.x; As[kq*4+1][li] = av.y;
            As[kq*4+2][li] = av.z; As[kq*4+3][li] = av.w;
            Bs[kq*4+0][li] = bv.x; Bs[kq*4+1][li] = bv.y;
            Bs[kq*4+2][li] = bv.z; Bs[kq*4+3][li] = bv.w;
            __syncthreads();
#pragma unroll
            for (int k = 0; k < 16; ++k) {
                float4 a = *(const float4*)&As[k][ty * 4];
                float4 b = *(const float4*)&Bs[k][tx * 4];
                float ar[4] = {a.x, a.y, a.z, a.w};
                float br[4] = {b.x, b.y, b.z, b.w};
#pragma unroll
                for (int i = 0; i < 4; ++i)
#pragma unroll
                    for (int j = 0; j < 4; ++j) acc[i][j] += ar[i] * br[j];
            }
            __syncthreads();
        }

        float inv = 1.0f / (*normsq);
        float p = prob[0];
        int cnt = 0;
#pragma unroll
        for (int ii = 0; ii < 4; ++ii) {
            int row = r0 + ty * 4 + ii;
            float4 v;
            float w[4];
#pragma unroll
            for (int jj = 0; jj < 4; ++jj) {
                int col = c0 + tx * 4 + jj;
                float s = acc[ii][jj] * inv;
                float a = 0.f;
                if (gb == 0)   // only graph 0 sees A (local-index quirk)
                    a = (float)Acnt[row * NPG + col];
                float pre = s - p + ALPHA * a;
                w[jj] = pre > 0.f ? pre : 0.f;
                cnt += (pre > 0.f) ? 1 : 0;
            }
            v.x = w[0]; v.y = w[1]; v.z = w[2]; v.w = w[3];
            *(float4*)&out[(size_t)row * NN + c0 + tx * 4] = v;
        }

        redi[tid] = cnt;
        __syncthreads();
        for (int s = 128; s > 0; s >>= 1) {
            if (tid < s) redi[tid] += redi[tid + s];
            __syncthreads();
        }
        if (tid == 0) atomicAdd(nz, redi[0]);
    } else {
        // off-diagonal tile: enumerate 56 off-diag tile-cols per tile-row
        int idx = bt - 512;                 // [0, 3584)
        int tr = idx / 56;
        int k  = idx - tr * 56;
        int grp = tr >> 3;
        int tc = (k >= grp * 8) ? (k + 8) : k;
        int r0 = tr * 64, c0 = tc * 64;
        float4 z = make_float4(0.f, 0.f, 0.f, 0.f);
        int row = r0 + (tid >> 4);
        int col = c0 + (tid & 15) * 4;
#pragma unroll
        for (int ii = 0; ii < 4; ++ii)
            *(float4*)&out[(size_t)(row + ii * 16) * NN + col] = z;
    }
}

__global__ void k_fin(const int* __restrict__ nz, const float* __restrict__ prob,
                      float* __restrict__ out) {
    out[(size_t)NN * NN]     = (float)(*nz) / (float)NE;
    out[(size_t)NN * NN + 1] = prob[0];
}

extern "C" void kernel_launch(void* const* d_in, const int* in_sizes, int n_in,
                              void* d_out, int out_size, void* d_ws, size_t ws_size,
                              hipStream_t stream) {
    (void)in_sizes; (void)n_in; (void)out_size; (void)ws_size;
    const float* x    = (const float*)d_in[0];
    const float* W0   = (const float*)d_in[1];
    const float* b0   = (const float*)d_in[2];
    const float* prob = (const float*)d_in[3];
    const int*   ei   = (const int*)d_in[4];
    const int*   bat  = (const int*)d_in[5];
    float* out = (float*)d_out;
    char*  ws  = (char*)d_ws;

    int*   Acnt   = (int*)ws;
    int*   offs   = (int*)(ws + META_OFF);
    float* normsq = (float*)(ws + META_OFF + 32);
    int*   nz     = (int*)(ws + META_OFF + 36);

    // Xh after meta (aligned to 256B)
    float* Xh = (float*)(ws + ((META_OFF + 64 + 255) & ~(size_t)255));

    // zero Acnt + meta only (1 MiB + 64 B) — output zeroing is fused into k_fused
    hipMemsetAsync(ws, 0, ACNT_BYTES + 64, stream);

    k_offsets<<<1, 256, 0, stream>>>((const int4*)bat, offs);
    k_xhat<<<128, 256, 0, stream>>>(x, W0, b0, Xh, normsq);
    k_scatter<<<NE / 256, 256, 0, stream>>>(ei, bat, offs, Acnt);
    k_fused<<<4096, 256, 0, stream>>>(Xh, Acnt, normsq, prob, out, nz);
    k_fin<<<1, 1, 0, stream>>>(nz, prob, out);
}

// Round 4
// 111.346 us; speedup vs baseline: 4.8971x; 1.0839x over previous
//
#include <hip/hip_runtime.h>

// SimGRew: Wmat = relu(S - prob + 0.5*A_sel) * same-graph-block mask
//   S = (X_hat @ X_hat^T) / ||X_hat||_F^2,  X_hat = x @ W0^T + b0
//   A_sel[i,j] = A[batch[i], i, j] (local-index adjacency) -> nonzero only for
//   i,j < NPG, i.e. ONLY graph 0's diagonal block sees the +alpha*A term.
// Outputs flat: Wmat[N*N] f32, edge_ratio, prob.
//
// R4: 4 dispatches (was 6). No memset, no meta atomics: per-slot partials
// reduced at kernel boundaries. k_prep = xhat + offsets + Acnt-zero fused.

#define NN   4096
#define GG   8
#define NPG  512
#define FF   128
#define HH   128
#define NE   131072
#define ALPHA 0.5f

// ws layout (bytes):
//   [0, 1MiB)            Acnt   int[NPG*NPG]   (graph-0 adjacency only)
//   [1MiB +0, +32)       offs   int[8]
//   [1MiB +64, +576)     normp  float[128]     (per-xhat-block partials)
//   [1MiB +576, +580)    normsq float          (reduced scalar)
//   [1MiB +1024, +3072)  nzp    int[512]       (per-diag-block nnz)
//   [1MiB +4096, ...)    Xh     float[NN*HH]   (2 MiB)
#define ACNT_BYTES ((size_t)NPG * NPG * 4)
#define OFFS_OFF   (ACNT_BYTES)
#define NORMP_OFF  (ACNT_BYTES + 64)
#define NORMS_OFF  (ACNT_BYTES + 576)
#define NZP_OFF    (ACNT_BYTES + 1024)
#define XH_OFF     (ACNT_BYTES + 4096)

// blocks 0..127: xhat 64x64 tiles; block 128: offsets; blocks 129..192: zero Acnt
__global__ __launch_bounds__(256) void k_prep(const float* __restrict__ x,
                                              const float* __restrict__ W0,
                                              const float* __restrict__ b0,
                                              const int4* __restrict__ batch4,
                                              float* __restrict__ Xh,
                                              float* __restrict__ normp,
                                              int* __restrict__ offs,
                                              int* __restrict__ Acnt) {
    int bx = blockIdx.x;
    int tid = threadIdx.x;

    if (bx < 128) {
        // X_hat = x @ W0^T + b0 ; per-block norm partial to normp[bx].
        __shared__ float As[16][68];
        __shared__ float Bs[16][68];
        __shared__ float red[256];

        int tm = bx >> 1, tn = bx & 1;
        int r0 = tm * 64, j0 = tn * 64;
        int tx = tid & 15, ty = tid >> 4;
        int li = tid & 63, kq = tid >> 6;

        float acc[4][4];
#pragma unroll
        for (int i = 0; i < 4; ++i)
#pragma unroll
            for (int j = 0; j < 4; ++j) acc[i][j] = 0.f;

        for (int k0 = 0; k0 < FF; k0 += 16) {
            float4 av = *(const float4*)&x [(size_t)(r0 + li) * FF + k0 + kq * 4];
            float4 bv = *(const float4*)&W0[(size_t)(j0 + li) * FF + k0 + kq * 4];
            As[kq*4+0][li] = av.x; As[kq*4+1][li] = av.y;
            As[kq*4+2][li] = av.z; As[kq*4+3][li] = av.w;
            Bs[kq*4+0][li] = bv.x; Bs[kq*4+1][li] = bv.y;
            Bs[kq*4+2][li] = bv.z; Bs[kq*4+3][li] = bv.w;
            __syncthreads();
#pragma unroll
            for (int k = 0; k < 16; ++k) {
                float4 a = *(const float4*)&As[k][ty * 4];
                float4 b = *(const float4*)&Bs[k][tx * 4];
                float ar[4] = {a.x, a.y, a.z, a.w};
                float br[4] = {b.x, b.y, b.z, b.w};
#pragma unroll
                for (int i = 0; i < 4; ++i)
#pragma unroll
                    for (int j = 0; j < 4; ++j) acc[i][j] += ar[i] * br[j];
            }
            __syncthreads();
        }

        float4 bb = *(const float4*)&b0[j0 + tx * 4];
        float ss = 0.f;
#pragma unroll
        for (int ii = 0; ii < 4; ++ii) {
            int row = r0 + ty * 4 + ii;
            float4 v;
            v.x = acc[ii][0] + bb.x;
            v.y = acc[ii][1] + bb.y;
            v.z = acc[ii][2] + bb.z;
            v.w = acc[ii][3] + bb.w;
            *(float4*)&Xh[(size_t)row * HH + j0 + tx * 4] = v;
            ss += v.x * v.x + v.y * v.y + v.z * v.z + v.w * v.w;
        }

        red[tid] = ss;
        __syncthreads();
        for (int s = 128; s > 0; s >>= 1) {
            if (tid < s) red[tid] += red[tid + s];
            __syncthreads();
        }
        if (tid == 0) normp[bx] = red[0];
    } else if (bx == 128) {
        // graph offsets from batch histogram (batch sorted)
        __shared__ int cnt[GG];
        if (tid < GG) cnt[tid] = 0;
        __syncthreads();
        for (int i = tid; i < NN / 4; i += 256) {
            int4 b = batch4[i];
            atomicAdd(&cnt[b.x], 1); atomicAdd(&cnt[b.y], 1);
            atomicAdd(&cnt[b.z], 1); atomicAdd(&cnt[b.w], 1);
        }
        __syncthreads();
        if (tid == 0) {
            int run = 0;
            for (int g = 0; g < GG; ++g) { offs[g] = run; run += cnt[g]; }
        }
    } else {
        // zero Acnt: 64 blocks x 16 KiB each
        int zb = bx - 129;                       // 0..63
        float4 z = make_float4(0.f, 0.f, 0.f, 0.f);
        float4* dst = (float4*)Acnt + (size_t)zb * 1024;
#pragma unroll
        for (int k = 0; k < 4; ++k) dst[tid + k * 256] = z;
    }
}

// blocks 0..511: scatter graph-0 edges into Acnt; block 512: reduce normp -> normsq
__global__ __launch_bounds__(256) void k_scatter(const int* __restrict__ ei,
                                                 const int* __restrict__ batch,
                                                 const int* __restrict__ offs,
                                                 int* __restrict__ Acnt,
                                                 const float* __restrict__ normp,
                                                 float* __restrict__ normsq) {
    int bx = blockIdx.x;
    int tid = threadIdx.x;
    if (bx == 512) {
        __shared__ float red[128];
        if (tid < 128) red[tid] = normp[tid];
        __syncthreads();
        for (int s = 64; s > 0; s >>= 1) {
            if (tid < s) red[tid] += red[tid + s];
            __syncthreads();
        }
        if (tid == 0) *normsq = red[0];
        return;
    }
    int e = bx * 256 + tid;
    int src = ei[e], dst = ei[NE + e];
    int g = batch[src];
    if (g != 0) return;                          // only graph 0's block sees A
    int lu = src - offs[0];
    int lv = dst - offs[batch[dst]];
    if (lu >= 0 && lu < NPG && lv >= 0 && lv < NPG)
        atomicAdd(&Acnt[lu * NPG + lv], 1);
}

// 4096 blocks: first 512 diag-group tiles (GEMM+relu+A+nnz->nzp slot),
// remaining 3584 stream float4 zeros.
__global__ __launch_bounds__(256) void k_fused(const float* __restrict__ Xh,
                                               const int* __restrict__ Acnt,
                                               const float* __restrict__ normsq,
                                               const float* __restrict__ prob,
                                               float* __restrict__ out,
                                               int* __restrict__ nzp) {
    __shared__ float As[16][68];
    __shared__ float Bs[16][68];
    __shared__ int redi[256];

    int bt = blockIdx.x;
    int tid = threadIdx.x;

    if (bt < 512) {
        int gb = bt >> 6;
        int t  = bt & 63;
        int tm = t >> 3, tn = t & 7;
        int base = gb * NPG;
        int r0 = base + tm * 64, c0 = base + tn * 64;
        int tx = tid & 15, ty = tid >> 4;
        int li = tid & 63, kq = tid >> 6;

        float acc[4][4];
#pragma unroll
        for (int i = 0; i < 4; ++i)
#pragma unroll
            for (int j = 0; j < 4; ++j) acc[i][j] = 0.f;

        for (int k0 = 0; k0 < HH; k0 += 16) {
            float4 av = *(const float4*)&Xh[(size_t)(r0 + li) * HH + k0 + kq * 4];
            float4 bv = *(const float4*)&Xh[(size_t)(c0 + li) * HH + k0 + kq * 4];
            As[kq*4+0][li] = av.x; As[kq*4+1][li] = av.y;
            As[kq*4+2][li] = av.z; As[kq*4+3][li] = av.w;
            Bs[kq*4+0][li] = bv.x; Bs[kq*4+1][li] = bv.y;
            Bs[kq*4+2][li] = bv.z; Bs[kq*4+3][li] = bv.w;
            __syncthreads();
#pragma unroll
            for (int k = 0; k < 16; ++k) {
                float4 a = *(const float4*)&As[k][ty * 4];
                float4 b = *(const float4*)&Bs[k][tx * 4];
                float ar[4] = {a.x, a.y, a.z, a.w};
                float br[4] = {b.x, b.y, b.z, b.w};
#pragma unroll
                for (int i = 0; i < 4; ++i)
#pragma unroll
                    for (int j = 0; j < 4; ++j) acc[i][j] += ar[i] * br[j];
            }
            __syncthreads();
        }

        float inv = 1.0f / (*normsq);
        float p = prob[0];
        int cnt = 0;
#pragma unroll
        for (int ii = 0; ii < 4; ++ii) {
            int row = r0 + ty * 4 + ii;
            float4 v;
            float w[4];
#pragma unroll
            for (int jj = 0; jj < 4; ++jj) {
                int col = c0 + tx * 4 + jj;
                float s = acc[ii][jj] * inv;
                float a = 0.f;
                if (gb == 0)                     // only graph 0 (local-index quirk)
                    a = (float)Acnt[row * NPG + col];
                float pre = s - p + ALPHA * a;
                w[jj] = pre > 0.f ? pre : 0.f;
                cnt += (pre > 0.f) ? 1 : 0;
            }
            v.x = w[0]; v.y = w[1]; v.z = w[2]; v.w = w[3];
            *(float4*)&out[(size_t)row * NN + c0 + tx * 4] = v;
        }

        redi[tid] = cnt;
        __syncthreads();
        for (int s = 128; s > 0; s >>= 1) {
            if (tid < s) redi[tid] += redi[tid + s];
            __syncthreads();
        }
        if (tid == 0) nzp[bt] = redi[0];
    } else {
        int idx = bt - 512;                      // [0, 3584)
        int tr = idx / 56;
        int k  = idx - tr * 56;
        int grp = tr >> 3;
        int tc = (k >= grp * 8) ? (k + 8) : k;
        int r0 = tr * 64, c0 = tc * 64;
        float4 z = make_float4(0.f, 0.f, 0.f, 0.f);
        int row = r0 + (tid >> 4);
        int col = c0 + (tid & 15) * 4;
#pragma unroll
        for (int ii = 0; ii < 4; ++ii)
            *(float4*)&out[(size_t)(row + ii * 16) * NN + col] = z;
    }
}

__global__ __launch_bounds__(256) void k_fin(const int* __restrict__ nzp,
                                             const float* __restrict__ prob,
                                             float* __restrict__ out) {
    __shared__ int red[256];
    int tid = threadIdx.x;
    red[tid] = nzp[tid] + nzp[tid + 256];
    __syncthreads();
    for (int s = 128; s > 0; s >>= 1) {
        if (tid < s) red[tid] += red[tid + s];
        __syncthreads();
    }
    if (tid == 0) {
        out[(size_t)NN * NN]     = (float)red[0] / (float)NE;
        out[(size_t)NN * NN + 1] = prob[0];
    }
}

extern "C" void kernel_launch(void* const* d_in, const int* in_sizes, int n_in,
                              void* d_out, int out_size, void* d_ws, size_t ws_size,
                              hipStream_t stream) {
    (void)in_sizes; (void)n_in; (void)out_size; (void)ws_size;
    const float* x    = (const float*)d_in[0];
    const float* W0   = (const float*)d_in[1];
    const float* b0   = (const float*)d_in[2];
    const float* prob = (const float*)d_in[3];
    const int*   ei   = (const int*)d_in[4];
    const int*   bat  = (const int*)d_in[5];
    float* out = (float*)d_out;
    char*  ws  = (char*)d_ws;

    int*   Acnt   = (int*)ws;
    int*   offs   = (int*)(ws + OFFS_OFF);
    float* normp  = (float*)(ws + NORMP_OFF);
    float* normsq = (float*)(ws + NORMS_OFF);
    int*   nzp    = (int*)(ws + NZP_OFF);
    float* Xh     = (float*)(ws + XH_OFF);

    k_prep<<<193, 256, 0, stream>>>(x, W0, b0, (const int4*)bat, Xh, normp, offs, Acnt);
    k_scatter<<<513, 256, 0, stream>>>(ei, bat, offs, Acnt, normp, normsq);
    k_fused<<<4096, 256, 0, stream>>>(Xh, Acnt, normsq, prob, out, nzp);
    k_fin<<<1, 256, 0, stream>>>(nzp, prob, out);
}